// Round 10
// baseline (99.181 us; speedup 1.0000x reference)
//
#include <hip/hip_runtime.h>

#define Bc 64
#define Sc 512
#define Dc 768
#define NLc 9
#define Lc 11
#define START (Lc-2)
#define ENDL (Lc-1)
#define NEGC -10000.0f
#define LOG2E 1.4426950408889634f
#define LN2 0.6931471805599453f
#define CHUNK 16
#define NCH (Sc / CHUNK)   // 32

// K1: logits[b,s,l] = dot(inputs[b,s,:], W[l,:]) + bias[l]
// R4 structure (best measured ~47us): 256-thread blocks, grid=1024, (256,4).
// wave = 4 segments of 16 lanes, one row per segment; 2 quads per wave.
// Depth-1 software pipeline with named scalars.
__global__ __launch_bounds__(256, 4) void k_logits(const float* __restrict__ x,
    const float* __restrict__ W, const float* __restrict__ bias,
    float* __restrict__ out)
{
  __shared__ float Wl[NLc * Dc];            // 27648 B
  {
    const float4* Wsrc = reinterpret_cast<const float4*>(W);
    float4* Wdst = reinterpret_cast<float4*>(Wl);
    for (int i = threadIdx.x; i < (NLc * Dc) / 4; i += 256) Wdst[i] = Wsrc[i];
  }
  __syncthreads();
  const int lane = threadIdx.x & 63;
  const int wid  = threadIdx.x >> 6;        // wave in block 0..3
  const int seg  = lane >> 4;               // 0..3
  const int sl   = lane & 15;               // 0..15
  const int gw   = blockIdx.x * 4 + wid;    // global wave id
  const int nwaves = gridDim.x * 4;         // 4096
  const int quads = (Bc * Sc) / 4;          // 8192

#pragma unroll 1
  for (int q = gw; q < quads; q += nwaves) {
    const int row = q * 4 + seg;
    const float4* xr = reinterpret_cast<const float4*>(x + (size_t)row * Dc);
    float acc[NLc];
#pragma unroll
    for (int l = 0; l < NLc; l++) acc[l] = 0.f;

    float4 xv = xr[sl];                     // first chunk in flight
#pragma unroll 1
    for (int j = 0; j < Dc / 64 - 1; ++j) { // 11 pipelined steps
      const float4 xn = xr[(j + 1) * 16 + sl];
      const float* wbase = Wl + j * 64 + sl * 4;
#pragma unroll
      for (int l = 0; l < NLc; l++) {
        const float4 wv = *reinterpret_cast<const float4*>(wbase + l * Dc);
        acc[l] = fmaf(xv.x, wv.x, acc[l]);
        acc[l] = fmaf(xv.y, wv.y, acc[l]);
        acc[l] = fmaf(xv.z, wv.z, acc[l]);
        acc[l] = fmaf(xv.w, wv.w, acc[l]);
      }
      xv = xn;
    }
    {                                       // last step
      const float* wbase = Wl + (Dc / 64 - 1) * 64 + sl * 4;
#pragma unroll
      for (int l = 0; l < NLc; l++) {
        const float4 wv = *reinterpret_cast<const float4*>(wbase + l * Dc);
        acc[l] = fmaf(xv.x, wv.x, acc[l]);
        acc[l] = fmaf(xv.y, wv.y, acc[l]);
        acc[l] = fmaf(xv.z, wv.z, acc[l]);
        acc[l] = fmaf(xv.w, wv.w, acc[l]);
      }
    }
#pragma unroll
    for (int off = 8; off >= 1; off >>= 1)
#pragma unroll
      for (int l = 0; l < NLc; l++)
        acc[l] += __shfl_xor(acc[l], off, 16);
    float v = acc[0];
#pragma unroll
    for (int l = 1; l < NLc; l++) v = (sl == l) ? acc[l] : v;
    if (sl < NLc) out[(size_t)row * NLc + sl] = v + bias[sl];
  }
}

// ---- PROBE A: pure x stream in k_logits' exact 16-lane-segment pattern ----
__global__ __launch_bounds__(256, 4) void k_probeA_seg(const float* __restrict__ x,
    float* __restrict__ o)
{
  const int lane = threadIdx.x & 63;
  const int wid  = threadIdx.x >> 6;
  const int seg  = lane >> 4;
  const int sl   = lane & 15;
  const int gw   = blockIdx.x * 4 + wid;
  float s = 0.f;
#pragma unroll 1
  for (int pass = 0; pass < 2; ++pass) {
    const int row = (gw + pass * 4096) * 4 + seg;
    const float4* xr = reinterpret_cast<const float4*>(x + (size_t)row * Dc);
#pragma unroll
    for (int j = 0; j < 12; ++j) {
      const float4 v = xr[j * 16 + sl];
      s += v.x + v.y + v.z + v.w;
    }
  }
  o[blockIdx.x * 256 + threadIdx.x] = s;
}

// ---- PROBE B: canonical contiguous grid-stride float4 stream (m13-style) ----
__global__ __launch_bounds__(256) void k_probeB_flat(const float* __restrict__ x,
    float* __restrict__ o)
{
  const int gtid = blockIdx.x * 256 + threadIdx.x;
  const int nthr = gridDim.x * 256;           // 1048576
  const float4* x4 = reinterpret_cast<const float4*>(x);
  float s0 = 0.f, s1 = 0.f;
#pragma unroll
  for (int k = 0; k < 6; k += 2) {            // 6291456 = 6 * nthr exactly
    const float4 a = x4[gtid + (size_t)k * nthr];
    const float4 b = x4[gtid + (size_t)(k + 1) * nthr];
    s0 += a.x + a.y + a.z + a.w;
    s1 += b.x + b.y + b.z + b.w;
  }
  o[gtid] = s0 + s1;
}

// Phase 1: per (batch, chunk) 11x11 log-semiring transfer matrix.
// Mout[(b*NCH+c)*121 + j*11 + i] = M[i][j]. Zeroes k_batch counter (block 0).
__global__ __launch_bounds__(64) void k_chunk(const float* __restrict__ logits,
    const int* __restrict__ mask, const float* __restrict__ trans,
    float* __restrict__ Mout, unsigned* __restrict__ cnt)
{
  if (blockIdx.x == 0 && threadIdx.x == 0) cnt[0] = 0u;
  const int b = blockIdx.x / NCH;
  const int c = blockIdx.x % NCH;
  const int lane = threadIdx.x;
  __shared__ float Mbuf[2][121];
  __shared__ float Llog[CHUNK][NLc];

  int len = 0;
  for (int t = lane; t < Sc; t += 64) len += mask[b * Sc + t];
#pragma unroll
  for (int off = 32; off >= 1; off >>= 1) len += __shfl_xor(len, off);

  for (int i = lane; i < CHUNK * NLc; i += 64) {
    const int t = i / NLc, l = i % NLc;
    Llog[t][l] = logits[((size_t)b * Sc + c * CHUNK + t) * NLc + l];
  }
  for (int e = lane; e < 121; e += 64) {
    const int i = e % Lc, j = e / Lc;
    Mbuf[0][e] = (i == j) ? 0.f : NEGC;
  }
  const int e1 = lane;          const bool v1 = (e1 < 121);
  const int e2 = lane + 64;     const bool v2 = (e2 < 121);
  const int i1 = v1 ? (e1 % Lc) : 0, j1 = v1 ? (e1 / Lc) : 0;
  const int i2 = v2 ? (e2 % Lc) : 0, j2 = v2 ? (e2 / Lc) : 0;
  float trow1[Lc], trow2[Lc];
#pragma unroll
  for (int k = 0; k < Lc; k++) {
    trow1[k] = trans[i1 * Lc + k];
    trow2[k] = trans[i2 * Lc + k];
  }
  __syncthreads();

  int p = 0;
  for (int t = 0; t < CHUNK; ++t) {
    const int tg = c * CHUNK + t;
    if (tg < len) {   // uniform across block
      const float lg1 = (i1 < NLc) ? Llog[t][i1] : NEGC;
      const float lg2 = (i2 < NLc) ? Llog[t][i2] : NEGC;
      float terms[Lc];
      float m1 = -3.0e38f;
#pragma unroll
      for (int k = 0; k < Lc; k++) {
        terms[k] = trow1[k] + Mbuf[p][j1 * Lc + k];
        m1 = fmaxf(m1, terms[k]);
      }
      float s1 = 0.f;
#pragma unroll
      for (int k = 0; k < Lc; k++) s1 += exp2f((terms[k] - m1) * LOG2E);
      const float n1 = lg1 + m1 + log2f(s1) * LN2;
      float m2 = -3.0e38f;
#pragma unroll
      for (int k = 0; k < Lc; k++) {
        terms[k] = trow2[k] + Mbuf[p][j2 * Lc + k];
        m2 = fmaxf(m2, terms[k]);
      }
      float s2 = 0.f;
#pragma unroll
      for (int k = 0; k < Lc; k++) s2 += exp2f((terms[k] - m2) * LOG2E);
      const float n2 = lg2 + m2 + log2f(s2) * LN2;
      if (v1) Mbuf[p ^ 1][e1] = n1;
      if (v2) Mbuf[p ^ 1][e2] = n2;
      p ^= 1;
    }
    __syncthreads();
  }
  for (int e = lane; e < 121; e += 64)
    Mout[((size_t)b * NCH + c) * 121 + e] = Mbuf[p][e];
}

// K_batch: wave 0 combine (norm), waves 1-3 unary+binary; last block reduces.
__global__ __launch_bounds__(256) void k_batch(const float* __restrict__ logits,
    const int* __restrict__ mask, const int* __restrict__ labels,
    const float* __restrict__ trans, const float* __restrict__ Min,
    float* __restrict__ part, unsigned* __restrict__ cnt,
    float* __restrict__ out)
{
  const int b = blockIdx.x;
  const int tid = threadIdx.x;
  const int wid = tid >> 6;
  const int lane = tid & 63;
  const int sl = lane & 15;
  __shared__ float Ms[NCH * 121];
  __shared__ int   ls[4];
  __shared__ float fs[4];
  __shared__ int   len_sh;
  __shared__ float norm_sh;
  __shared__ int   do_final;

  {
    const float4* src = reinterpret_cast<const float4*>(Min + (size_t)b * NCH * 121);
    for (int i = tid; i < (NCH * 121) / 4; i += 256)
      reinterpret_cast<float4*>(Ms)[i] = src[i];
  }
  int lp = 0;
  for (int t = tid; t < Sc; t += 256) lp += mask[b * Sc + t];
#pragma unroll
  for (int off = 32; off >= 1; off >>= 1) lp += __shfl_down(lp, off);
  if (lane == 0) ls[wid] = lp;
  __syncthreads();
  if (tid == 0) len_sh = ls[0] + ls[1] + ls[2] + ls[3];
  __syncthreads();
  const int len = len_sh;

  if (wid == 0) {
    const int ii = (sl < Lc) ? sl : 0;
    float alpha = (sl == START) ? 0.f : NEGC;
#pragma unroll 1
    for (int c = 0; c < NCH; ++c) {
      const float* M = Ms + c * 121;
      float terms[Lc];
      float m = -3.0e38f;
#pragma unroll
      for (int k = 0; k < Lc; k++) {
        const float ak = __shfl(alpha, k, 16);
        terms[k] = M[k * Lc + ii] + ak;
        m = fmaxf(m, terms[k]);
      }
      float s = 0.f;
#pragma unroll
      for (int k = 0; k < Lc; k++) s += exp2f((terms[k] - m) * LOG2E);
      const float anew = m + log2f(s) * LN2;
      alpha = (sl < Lc) ? anew : alpha;
    }
    float v = (sl < Lc) ? (alpha + trans[ENDL * Lc + sl]) : -3.0e38f;
    float mm = v;
#pragma unroll
    for (int off = 8; off >= 1; off >>= 1) mm = fmaxf(mm, __shfl_xor(mm, off, 16));
    float se = exp2f((v - mm) * LOG2E);
#pragma unroll
    for (int off = 8; off >= 1; off >>= 1) se += __shfl_xor(se, off, 16);
    if (lane == 0) norm_sh = mm + log2f(se) * LN2;
  } else {
    float u = 0.f;
    for (int t = tid - 64; t < Sc; t += 192)
      if (t < len) u += logits[((size_t)b * Sc + t) * NLc + labels[b * Sc + t]];
    for (int t = tid - 64; t <= Sc; t += 192) {
      if (t <= len) {
        const int cur = (t == 0) ? START : ((t - 1 < len) ? labels[b * Sc + t - 1] : ENDL);
        const int nxt = (t < len) ? labels[b * Sc + t] : ENDL;
        u += trans[nxt * Lc + cur];
      }
    }
#pragma unroll
    for (int off = 32; off >= 1; off >>= 1) u += __shfl_down(u, off);
    if (lane == 0) fs[wid] = u;
  }
  __syncthreads();

  if (tid == 0) {
    const float pb = fs[1] + fs[2] + fs[3] - norm_sh;
    __hip_atomic_store(&part[b], pb, __ATOMIC_RELEASE, __HIP_MEMORY_SCOPE_AGENT);
    const unsigned old = __hip_atomic_fetch_add(cnt, 1u, __ATOMIC_ACQ_REL,
                                                __HIP_MEMORY_SCOPE_AGENT);
    do_final = (old == (unsigned)(Bc - 1)) ? 1 : 0;
  }
  __syncthreads();
  if (do_final && wid == 0) {
    float v = __hip_atomic_load(&part[lane], __ATOMIC_RELAXED,
                                __HIP_MEMORY_SCOPE_AGENT);
#pragma unroll
    for (int off = 32; off >= 1; off >>= 1) v += __shfl_xor(v, off);
    if (lane == 0) out[0] = -v * (1.0f / Bc);
  }
}

extern "C" void kernel_launch(void* const* d_in, const int* in_sizes, int n_in,
                              void* d_out, int out_size, void* d_ws, size_t ws_size,
                              hipStream_t stream)
{
  const float* x      = (const float*)d_in[0];
  const int*   mask   = (const int*)d_in[1];
  const int*   labels = (const int*)d_in[2];
  const float* W      = (const float*)d_in[3];
  const float* bias   = (const float*)d_in[4];
  const float* trans  = (const float*)d_in[5];
  float* out = (float*)d_out;
  float* ws  = (float*)d_ws;

  float*    ws_logits = ws;                                  // B*S*NL floats
  float*    ws_M      = ws_logits + (size_t)Bc * Sc * NLc;   // B*NCH*121 floats
  float*    ws_part   = ws_M + (size_t)Bc * NCH * 121;       // B floats
  unsigned* ws_cnt    = (unsigned*)(ws_part + Bc);           // 1 uint
  float*    ws_pA     = ws + 600000;                         // 262144 floats
  float*    ws_pB     = ws + 900000;                         // 1048576 floats

  hipLaunchKernelGGL(k_logits, dim3(1024), dim3(256), 0, stream, x, W, bias, ws_logits);
  hipLaunchKernelGGL(k_chunk,  dim3(Bc * NCH), dim3(64), 0, stream, ws_logits, mask, trans, ws_M, ws_cnt);
  hipLaunchKernelGGL(k_batch,  dim3(Bc), dim3(256), 0, stream, ws_logits, mask, labels, trans, ws_M, ws_part, ws_cnt, out);
  // ---- diagnostics (read x only; outputs to scratch) ----
  hipLaunchKernelGGL(k_probeA_seg,  dim3(1024), dim3(256), 0, stream, x, ws_pA);
  hipLaunchKernelGGL(k_probeB_flat, dim3(4096), dim3(256), 0, stream, x, ws_pB);
}

// Round 11
// 61.740 us; speedup vs baseline: 1.6064x; 1.6064x over previous
//
#include <hip/hip_runtime.h>

#define Bc 64
#define Sc 512
#define Dc 768
#define NLc 9
#define Lc 11
#define START (Lc-2)
#define ENDL (Lc-1)
#define NEGC -10000.0f
#define LOG2E 1.4426950408889634f
#define LN2 0.6931471805599453f
#define CHUNK 16
#define NCH (Sc / CHUNK)   // 32

// K1: logits[b,s,l] = dot(inputs[b,s,:], W[l,:]) + bias[l]
// v6: probeA-style load schedule. Wave = 4 segments x 16 lanes; each segment
// owns TWO adjacent rows; ALL 24 row-loads (2 rows x 12 float4) issued up
// front as NAMED scalars (R10: probeA with 12 back-to-back loads streams 3x
// faster than the depth-1 pipeline; depth-1 keeps only 1-2 loads in flight).
// Compiler emits descending vmcnt(N) waits -> deep pipeline, no per-step gap.
// W segment-broadcast LDS reads serve 8 rows per 9 ds_read_b128 (halved
// per-row LDS traffic). ~130 live VGPR -> (256,3), 12 waves/CU.
__global__ __launch_bounds__(256, 3) void k_logits(const float* __restrict__ x,
    const float* __restrict__ W, const float* __restrict__ bias,
    float* __restrict__ out)
{
  __shared__ float Wl[NLc * Dc];            // 27648 B
  {
    const float4* Wsrc = reinterpret_cast<const float4*>(W);
    float4* Wdst = reinterpret_cast<float4*>(Wl);
    for (int i = threadIdx.x; i < (NLc * Dc) / 4; i += 256) Wdst[i] = Wsrc[i];
  }
  __syncthreads();
  const int lane = threadIdx.x & 63;
  const int wid  = threadIdx.x >> 6;        // wave in block 0..3
  const int seg  = lane >> 4;               // 0..3
  const int sl   = lane & 15;               // 0..15
  const int gw   = blockIdx.x * 4 + wid;    // global wave id 0..4095

  const int rowA = gw * 8 + seg * 2;        // rows rowA, rowA+1 (8 rows/wave)
  const float4* xa = reinterpret_cast<const float4*>(x + (size_t)rowA * Dc);
  const float4* xb = reinterpret_cast<const float4*>(x + (size_t)(rowA + 1) * Dc);

  // ---- burst: all 24 loads issued back-to-back (named scalars only) ----
  float4 a0  = xa[0 * 16 + sl],  b0  = xb[0 * 16 + sl];
  float4 a1  = xa[1 * 16 + sl],  b1  = xb[1 * 16 + sl];
  float4 a2  = xa[2 * 16 + sl],  b2  = xb[2 * 16 + sl];
  float4 a3  = xa[3 * 16 + sl],  b3  = xb[3 * 16 + sl];
  float4 a4  = xa[4 * 16 + sl],  b4  = xb[4 * 16 + sl];
  float4 a5  = xa[5 * 16 + sl],  b5  = xb[5 * 16 + sl];
  float4 a6  = xa[6 * 16 + sl],  b6  = xb[6 * 16 + sl];
  float4 a7  = xa[7 * 16 + sl],  b7  = xb[7 * 16 + sl];
  float4 a8  = xa[8 * 16 + sl],  b8  = xb[8 * 16 + sl];
  float4 a9  = xa[9 * 16 + sl],  b9  = xb[9 * 16 + sl];
  float4 a10 = xa[10 * 16 + sl], b10 = xb[10 * 16 + sl];
  float4 a11 = xa[11 * 16 + sl], b11 = xb[11 * 16 + sl];

  float accA[NLc], accB[NLc];
#pragma unroll
  for (int l = 0; l < NLc; l++) { accA[l] = 0.f; accB[l] = 0.f; }

#define STEP(XA, XB, J)                                                        \
  {                                                                            \
    const float* wb = Wl + (J) * 64 + sl * 4;                                  \
    _Pragma("unroll")                                                          \
    for (int l = 0; l < NLc; l++) {                                            \
      const float4 wv = *reinterpret_cast<const float4*>(wb + l * Dc);         \
      accA[l] = fmaf((XA).x, wv.x, accA[l]);                                   \
      accB[l] = fmaf((XB).x, wv.x, accB[l]);                                   \
      accA[l] = fmaf((XA).y, wv.y, accA[l]);                                   \
      accB[l] = fmaf((XB).y, wv.y, accB[l]);                                   \
      accA[l] = fmaf((XA).z, wv.z, accA[l]);                                   \
      accB[l] = fmaf((XB).z, wv.z, accB[l]);                                   \
      accA[l] = fmaf((XA).w, wv.w, accA[l]);                                   \
      accB[l] = fmaf((XB).w, wv.w, accB[l]);                                   \
    }                                                                          \
  }
  STEP(a0, b0, 0)   STEP(a1, b1, 1)   STEP(a2, b2, 2)
  STEP(a3, b3, 3)   STEP(a4, b4, 4)   STEP(a5, b5, 5)
  STEP(a6, b6, 6)   STEP(a7, b7, 7)   STEP(a8, b8, 8)
  STEP(a9, b9, 9)   STEP(a10, b10, 10) STEP(a11, b11, 11)
#undef STEP

  // butterfly reduce within each 16-lane segment (both rows)
#pragma unroll
  for (int off = 8; off >= 1; off >>= 1)
#pragma unroll
    for (int l = 0; l < NLc; l++) {
      accA[l] += __shfl_xor(accA[l], off, 16);
      accB[l] += __shfl_xor(accB[l], off, 16);
    }
  // lane sl (<9) stores label sl for both rows (2 x 36 B consecutive)
  float vA = accA[0], vB = accB[0];
#pragma unroll
  for (int l = 1; l < NLc; l++) {
    vA = (sl == l) ? accA[l] : vA;
    vB = (sl == l) ? accB[l] : vB;
  }
  if (sl < NLc) {
    const float bb = bias[sl];
    out[(size_t)rowA * NLc + sl]       = vA + bb;
    out[(size_t)(rowA + 1) * NLc + sl] = vB + bb;
  }
}

// Phase 1: per (batch, chunk) 11x11 log-semiring transfer matrix.
// Mout[(b*NCH+c)*121 + j*11 + i] = M[i][j]. Zeroes k_batch counter (block 0).
__global__ __launch_bounds__(64) void k_chunk(const float* __restrict__ logits,
    const int* __restrict__ mask, const float* __restrict__ trans,
    float* __restrict__ Mout, unsigned* __restrict__ cnt)
{
  if (blockIdx.x == 0 && threadIdx.x == 0) cnt[0] = 0u;
  const int b = blockIdx.x / NCH;
  const int c = blockIdx.x % NCH;
  const int lane = threadIdx.x;
  __shared__ float Mbuf[2][121];
  __shared__ float Llog[CHUNK][NLc];

  int len = 0;
  for (int t = lane; t < Sc; t += 64) len += mask[b * Sc + t];
#pragma unroll
  for (int off = 32; off >= 1; off >>= 1) len += __shfl_xor(len, off);

  for (int i = lane; i < CHUNK * NLc; i += 64) {
    const int t = i / NLc, l = i % NLc;
    Llog[t][l] = logits[((size_t)b * Sc + c * CHUNK + t) * NLc + l];
  }
  for (int e = lane; e < 121; e += 64) {
    const int i = e % Lc, j = e / Lc;
    Mbuf[0][e] = (i == j) ? 0.f : NEGC;
  }
  const int e1 = lane;          const bool v1 = (e1 < 121);
  const int e2 = lane + 64;     const bool v2 = (e2 < 121);
  const int i1 = v1 ? (e1 % Lc) : 0, j1 = v1 ? (e1 / Lc) : 0;
  const int i2 = v2 ? (e2 % Lc) : 0, j2 = v2 ? (e2 / Lc) : 0;
  float trow1[Lc], trow2[Lc];
#pragma unroll
  for (int k = 0; k < Lc; k++) {
    trow1[k] = trans[i1 * Lc + k];
    trow2[k] = trans[i2 * Lc + k];
  }
  __syncthreads();

  int p = 0;
  for (int t = 0; t < CHUNK; ++t) {
    const int tg = c * CHUNK + t;
    if (tg < len) {   // uniform across block
      const float lg1 = (i1 < NLc) ? Llog[t][i1] : NEGC;
      const float lg2 = (i2 < NLc) ? Llog[t][i2] : NEGC;
      float terms[Lc];
      float m1 = -3.0e38f;
#pragma unroll
      for (int k = 0; k < Lc; k++) {
        terms[k] = trow1[k] + Mbuf[p][j1 * Lc + k];
        m1 = fmaxf(m1, terms[k]);
      }
      float s1 = 0.f;
#pragma unroll
      for (int k = 0; k < Lc; k++) s1 += exp2f((terms[k] - m1) * LOG2E);
      const float n1 = lg1 + m1 + log2f(s1) * LN2;
      float m2 = -3.0e38f;
#pragma unroll
      for (int k = 0; k < Lc; k++) {
        terms[k] = trow2[k] + Mbuf[p][j2 * Lc + k];
        m2 = fmaxf(m2, terms[k]);
      }
      float s2 = 0.f;
#pragma unroll
      for (int k = 0; k < Lc; k++) s2 += exp2f((terms[k] - m2) * LOG2E);
      const float n2 = lg2 + m2 + log2f(s2) * LN2;
      if (v1) Mbuf[p ^ 1][e1] = n1;
      if (v2) Mbuf[p ^ 1][e2] = n2;
      p ^= 1;
    }
    __syncthreads();
  }
  for (int e = lane; e < 121; e += 64)
    Mout[((size_t)b * NCH + c) * 121 + e] = Mbuf[p][e];
}

// K_batch: wave 0 combine (norm), waves 1-3 unary+binary; last block reduces.
__global__ __launch_bounds__(256) void k_batch(const float* __restrict__ logits,
    const int* __restrict__ mask, const int* __restrict__ labels,
    const float* __restrict__ trans, const float* __restrict__ Min,
    float* __restrict__ part, unsigned* __restrict__ cnt,
    float* __restrict__ out)
{
  const int b = blockIdx.x;
  const int tid = threadIdx.x;
  const int wid = tid >> 6;
  const int lane = tid & 63;
  const int sl = lane & 15;
  __shared__ float Ms[NCH * 121];
  __shared__ int   ls[4];
  __shared__ float fs[4];
  __shared__ int   len_sh;
  __shared__ float norm_sh;
  __shared__ int   do_final;

  {
    const float4* src = reinterpret_cast<const float4*>(Min + (size_t)b * NCH * 121);
    for (int i = tid; i < (NCH * 121) / 4; i += 256)
      reinterpret_cast<float4*>(Ms)[i] = src[i];
  }
  int lp = 0;
  for (int t = tid; t < Sc; t += 256) lp += mask[b * Sc + t];
#pragma unroll
  for (int off = 32; off >= 1; off >>= 1) lp += __shfl_down(lp, off);
  if (lane == 0) ls[wid] = lp;
  __syncthreads();
  if (tid == 0) len_sh = ls[0] + ls[1] + ls[2] + ls[3];
  __syncthreads();
  const int len = len_sh;

  if (wid == 0) {
    const int ii = (sl < Lc) ? sl : 0;
    float alpha = (sl == START) ? 0.f : NEGC;
#pragma unroll 1
    for (int c = 0; c < NCH; ++c) {
      const float* M = Ms + c * 121;
      float terms[Lc];
      float m = -3.0e38f;
#pragma unroll
      for (int k = 0; k < Lc; k++) {
        const float ak = __shfl(alpha, k, 16);
        terms[k] = M[k * Lc + ii] + ak;
        m = fmaxf(m, terms[k]);
      }
      float s = 0.f;
#pragma unroll
      for (int k = 0; k < Lc; k++) s += exp2f((terms[k] - m) * LOG2E);
      const float anew = m + log2f(s) * LN2;
      alpha = (sl < Lc) ? anew : alpha;
    }
    float v = (sl < Lc) ? (alpha + trans[ENDL * Lc + sl]) : -3.0e38f;
    float mm = v;
#pragma unroll
    for (int off = 8; off >= 1; off >>= 1) mm = fmaxf(mm, __shfl_xor(mm, off, 16));
    float se = exp2f((v - mm) * LOG2E);
#pragma unroll
    for (int off = 8; off >= 1; off >>= 1) se += __shfl_xor(se, off, 16);
    if (lane == 0) norm_sh = mm + log2f(se) * LN2;
  } else {
    float u = 0.f;
    for (int t = tid - 64; t < Sc; t += 192)
      if (t < len) u += logits[((size_t)b * Sc + t) * NLc + labels[b * Sc + t]];
    for (int t = tid - 64; t <= Sc; t += 192) {
      if (t <= len) {
        const int cur = (t == 0) ? START : ((t - 1 < len) ? labels[b * Sc + t - 1] : ENDL);
        const int nxt = (t < len) ? labels[b * Sc + t] : ENDL;
        u += trans[nxt * Lc + cur];
      }
    }
#pragma unroll
    for (int off = 32; off >= 1; off >>= 1) u += __shfl_down(u, off);
    if (lane == 0) fs[wid] = u;
  }
  __syncthreads();

  if (tid == 0) {
    const float pb = fs[1] + fs[2] + fs[3] - norm_sh;
    __hip_atomic_store(&part[b], pb, __ATOMIC_RELEASE, __HIP_MEMORY_SCOPE_AGENT);
    const unsigned old = __hip_atomic_fetch_add(cnt, 1u, __ATOMIC_ACQ_REL,
                                                __HIP_MEMORY_SCOPE_AGENT);
    do_final = (old == (unsigned)(Bc - 1)) ? 1 : 0;
  }
  __syncthreads();
  if (do_final && wid == 0) {
    float v = __hip_atomic_load(&part[lane], __ATOMIC_RELAXED,
                                __HIP_MEMORY_SCOPE_AGENT);
#pragma unroll
    for (int off = 32; off >= 1; off >>= 1) v += __shfl_xor(v, off);
    if (lane == 0) out[0] = -v * (1.0f / Bc);
  }
}

extern "C" void kernel_launch(void* const* d_in, const int* in_sizes, int n_in,
                              void* d_out, int out_size, void* d_ws, size_t ws_size,
                              hipStream_t stream)
{
  const float* x      = (const float*)d_in[0];
  const int*   mask   = (const int*)d_in[1];
  const int*   labels = (const int*)d_in[2];
  const float* W      = (const float*)d_in[3];
  const float* bias   = (const float*)d_in[4];
  const float* trans  = (const float*)d_in[5];
  float* out = (float*)d_out;
  float* ws  = (float*)d_ws;

  float*    ws_logits = ws;                                  // B*S*NL floats
  float*    ws_M      = ws_logits + (size_t)Bc * Sc * NLc;   // B*NCH*121 floats
  float*    ws_part   = ws_M + (size_t)Bc * NCH * 121;       // B floats
  unsigned* ws_cnt    = (unsigned*)(ws_part + Bc);           // 1 uint

  hipLaunchKernelGGL(k_logits, dim3(1024), dim3(256), 0, stream, x, W, bias, ws_logits);
  hipLaunchKernelGGL(k_chunk,  dim3(Bc * NCH), dim3(64), 0, stream, ws_logits, mask, trans, ws_M, ws_cnt);
  hipLaunchKernelGGL(k_batch,  dim3(Bc), dim3(256), 0, stream, ws_logits, mask, labels, trans, ws_M, ws_part, ws_cnt, out);
}